// Round 4
// baseline (65904.510 us; speedup 1.0000x reference)
//
#include <hip/hip_runtime.h>
#include <math.h>

#define Bsz 512
#define Tsz 1024
#define Vsz 27
#define Hsz 512
#define NBLK 256
#define BT 64      // batch rows per group (8 groups)
#define HPc 16     // h' cols per block (32 j-blocks)
#define NG 48      // gate rows per block = 3*HPc
#define WPAD 516   // padded K-stride for W_hh tile (2-way max bank conflict)

// swizzled float4 index within a 64x16(quads) h tile: involution c4 ^= (r&15)
__device__ __forceinline__ int hs_q(int r, int c4) {
    return (r << 4) + (c4 ^ (r & 15));
}

__device__ __forceinline__ void gload_lds16(const float* src, float* dst) {
    __builtin_amdgcn_global_load_lds(
        (const __attribute__((address_space(1))) unsigned int*)src,
        (__attribute__((address_space(3))) unsigned int*)dst, 16, 0, 0);
}

// zero h buffer 0 (read at i=0) and the 256 barrier counters
__global__ void init_ws_kernel(float* __restrict__ hbuf, unsigned* __restrict__ cnt) {
    int i = blockIdx.x * 256 + threadIdx.x;     // 256 blk x 256 thr x float4 = 1 MB
    ((float4*)hbuf)[i] = make_float4(0.f, 0.f, 0.f, 0.f);
    if (blockIdx.x == 0) cnt[threadIdx.x] = 0u;
}

__device__ __forceinline__ void group_barrier(unsigned* c, unsigned target) {
    __syncthreads();
    if (threadIdx.x == 0) {
        __threadfence();  // agent release: drain + write back this XCD's L2
        __hip_atomic_fetch_add(c, 1u, __ATOMIC_RELEASE, __HIP_MEMORY_SCOPE_AGENT);
        while (__hip_atomic_load(c, __ATOMIC_ACQUIRE, __HIP_MEMORY_SCOPE_AGENT) < target)
            __builtin_amdgcn_s_sleep(2);
        __threadfence();  // agent acquire: invalidate stale L1/L2 before reading h
    }
    __syncthreads();
}

__global__ __launch_bounds__(256) void gru_persist(
    const float* __restrict__ x, const float* __restrict__ W_ih,
    const float* __restrict__ W_hh, const float* __restrict__ b_ih,
    const float* __restrict__ b_hh, const float* __restrict__ W_dec,
    const float* __restrict__ b_dec, float* __restrict__ hbuf,
    unsigned* __restrict__ cnt, float* __restrict__ out)
{
    __shared__ float ws[NG][WPAD];      // persistent W_hh slice (97 KB)
    __shared__ float wi[NG][28];        // persistent W_ih slice
    __shared__ float xs[BT][28];        // per-step x tile
    __shared__ float wd[Hsz];           // W_dec row v=j (j<27)
    __shared__ float bih[NG], bhh[NG];
    __shared__ float hsf[2][64 * 64];   // double-buffered swizzled h chunk

    const int tid = threadIdx.x;
    const int bt  = blockIdx.x >> 5;    // batch group 0..7
    const int j   = blockIdx.x & 31;    // h' tile 0..31
    const int b0  = bt * BT;
    const int g0  = j * HPc;

    // ---- persistent staging (once) ----
    for (int idx = tid; idx < NG * (Hsz / 4); idx += 256) {
        int row = idx >> 7, c4 = idx & 127;
        int grow = (row < 16) ? (g0 + row) : (row < 32 ? Hsz + g0 + row - 16 : 2 * Hsz + g0 + row - 32);
        *(float4*)&ws[row][c4 << 2] = *(const float4*)&W_hh[(size_t)grow * Hsz + (c4 << 2)];
    }
    for (int idx = tid; idx < NG * Vsz; idx += 256) {
        int row = idx / Vsz, v = idx - row * Vsz;
        int grow = (row < 16) ? (g0 + row) : (row < 32 ? Hsz + g0 + row - 16 : 2 * Hsz + g0 + row - 32);
        wi[row][v] = W_ih[grow * Vsz + v];
    }
    if (tid < NG) {
        int grow = (tid < 16) ? (g0 + tid) : (tid < 32 ? Hsz + g0 + tid - 16 : 2 * Hsz + g0 + tid - 32);
        bih[tid] = b_ih[grow];
        bhh[tid] = b_hh[grow];
    }
    if (j < Vsz)
        for (int k = tid; k < Hsz; k += 256) wd[k] = W_dec[j * Hsz + k];
    const float bdec_s = (j < Vsz) ? b_dec[j] : 0.f;

    const int hp = tid & 15;            // h' col within tile
    const int bq = (tid >> 4) << 2;     // 4 batch rows per thread
    const int db = tid >> 2, dk = tid & 3;   // decode mapping
    const int wv = tid >> 6, ln = tid & 63;  // wave id / lane
    unsigned* mycnt = cnt + bt * 32;
    const int cj  = j >> 2;                        // chunk holding own h' slice
    const int c4o = ((j & 3) << 2) + (hp >> 2);    // its quad within chunk
    const int eo  = hp & 3;

    for (int i = 0; i <= Tsz; ++i) {
        const float* hprev = hbuf + (size_t)(i & 1) * (Bsz * Hsz);

        // issue chunk 0 into hsf[0] (pre-swizzled global source, linear LDS dest)
        {
            float* dstb = &hsf[0][0];
            #pragma unroll
            for (int ii = 0; ii < 4; ++ii) {
                int r = (wv << 4) + (ii << 2) + (ln >> 4);
                int c4g = (ln & 15) ^ (r & 15);
                gload_lds16(hprev + (size_t)(b0 + r) * Hsz + (c4g << 2),
                            dstb + (((wv << 4) + (ii << 2)) << 6));
            }
        }
        if (i < Tsz) {
            for (int idx = tid; idx < BT * Vsz; idx += 256) {
                int r = idx / Vsz, v = idx - r * Vsz;
                xs[r][v] = x[(size_t)(b0 + r) * (Tsz * Vsz) + (size_t)i * Vsz + v];
            }
        }
        __syncthreads();

        // ---- gi = x . W_ih^T + b_ih (K=27), from LDS ----
        float gr[4], gz[4], gn[4];
        #pragma unroll
        for (int q = 0; q < 4; ++q) { gr[q] = bih[hp]; gz[q] = bih[16 + hp]; gn[q] = bih[32 + hp]; }
        if (i < Tsz) {
            for (int v = 0; v < Vsz; ++v) {
                float wr_ = wi[hp][v], wz_ = wi[16 + hp][v], wn_ = wi[32 + hp][v];
                #pragma unroll
                for (int q = 0; q < 4; ++q) {
                    float xv = xs[bq + q][v];
                    gr[q] += xv * wr_; gz[q] += xv * wz_; gn[q] += xv * wn_;
                }
            }
        }

        float accr[4] = {0,0,0,0}, accz[4] = {0,0,0,0}, accn[4] = {0,0,0,0};
        float hkeep[4] = {0,0,0,0};
        float dec = 0.f;
        const bool doDec = (i > 0) && (j < Vsz);

        for (int c = 0; c < 8; ++c) {
            const float* hsc = &hsf[c & 1][0];
            if (c < 7) {   // prefetch next chunk
                float* dstb = &hsf[(c + 1) & 1][0];
                const int kc = (c + 1) << 6;
                #pragma unroll
                for (int ii = 0; ii < 4; ++ii) {
                    int r = (wv << 4) + (ii << 2) + (ln >> 4);
                    int c4g = (ln & 15) ^ (r & 15);
                    gload_lds16(hprev + (size_t)(b0 + r) * Hsz + kc + (c4g << 2),
                                dstb + (((wv << 4) + (ii << 2)) << 6));
                }
            }
            if (i < Tsz) {
                #pragma unroll
                for (int k4 = 0; k4 < 16; ++k4) {
                    const int kk = (c << 6) + (k4 << 2);
                    float4 wr4 = *(const float4*)&ws[hp][kk];
                    float4 wz4 = *(const float4*)&ws[16 + hp][kk];
                    float4 wn4 = *(const float4*)&ws[32 + hp][kk];
                    #pragma unroll
                    for (int q = 0; q < 4; ++q) {
                        float4 hv = *(const float4*)&hsc[hs_q(bq + q, k4) << 2];
                        accr[q] += hv.x * wr4.x + hv.y * wr4.y + hv.z * wr4.z + hv.w * wr4.w;
                        accz[q] += hv.x * wz4.x + hv.y * wz4.y + hv.z * wz4.z + hv.w * wz4.w;
                        accn[q] += hv.x * wn4.x + hv.y * wn4.y + hv.z * wn4.z + hv.w * wn4.w;
                    }
                }
                if (c == cj) {
                    #pragma unroll
                    for (int q = 0; q < 4; ++q)
                        hkeep[q] = hsc[(hs_q(bq + q, c4o) << 2) + eo];
                }
            }
            if (doDec) {   // decode h_{i-1} for v=j, split-K over 4 threads/batch
                #pragma unroll
                for (int ii = 0; ii < 4; ++ii) {
                    int c4 = (dk << 2) + ii;
                    float4 hv = *(const float4*)&hsc[hs_q(db, c4) << 2];
                    float4 wv4 = *(const float4*)&wd[(c << 6) + (c4 << 2)];
                    dec += hv.x * wv4.x + hv.y * wv4.y + hv.z * wv4.z + hv.w * wv4.w;
                }
            }
            if (c < 7) __syncthreads();
        }

        // ---- gates + h update ----
        if (i < Tsz) {
            float* hnext = hbuf + (size_t)((i + 1) & 1) * (Bsz * Hsz);
            #pragma unroll
            for (int q = 0; q < 4; ++q) {
                float hr = accr[q] + bhh[hp];
                float hz = accz[q] + bhh[16 + hp];
                float hn = accn[q] + bhh[32 + hp];
                float rg = 1.f / (1.f + expf(-(gr[q] + hr)));
                float zg = 1.f / (1.f + expf(-(gz[q] + hz)));
                float ng = tanhf(gn[q] + rg * hn);
                hnext[(size_t)(b0 + bq + q) * Hsz + g0 + hp] = (1.f - zg) * ng + zg * hkeep[q];
            }
        }
        if (doDec) {
            dec += __shfl_xor(dec, 1);
            dec += __shfl_xor(dec, 2);
            if (dk == 0)
                out[(size_t)(b0 + db) * (Tsz * Vsz) + (size_t)(i - 1) * Vsz + j] = dec + bdec_s;
        }
        if (i < Tsz) group_barrier(mycnt, 32u * (unsigned)(i + 1));
    }
}

extern "C" void kernel_launch(void* const* d_in, const int* in_sizes, int n_in,
                              void* d_out, int out_size, void* d_ws, size_t ws_size,
                              hipStream_t stream) {
    const float* x     = (const float*)d_in[0];
    const float* W_ih  = (const float*)d_in[1];
    const float* W_hh  = (const float*)d_in[2];
    const float* b_ih  = (const float*)d_in[3];
    const float* b_hh  = (const float*)d_in[4];
    const float* W_dec = (const float*)d_in[5];
    const float* b_dec = (const float*)d_in[6];
    float* out  = (float*)d_out;
    float* hbuf = (float*)d_ws;                                    // 2 x 1 MB double buffer
    unsigned* cnt = (unsigned*)((char*)d_ws + (size_t)2 * Bsz * Hsz * sizeof(float));

    init_ws_kernel<<<256, 256, 0, stream>>>(hbuf, cnt);

    // Plain launch: co-residency is structurally guaranteed (143 KB LDS ->
    // exactly 1 block/CU, grid == 256 == CU count), so the hand-rolled
    // group barriers cannot deadlock. hipLaunchCooperativeKernel silently
    // rejected this kernel (all-zero output, R2/R3).
    gru_persist<<<dim3(NBLK), dim3(256), 0, stream>>>(
        x, W_ih, W_hh, b_ih, b_hh, W_dec, b_dec, hbuf, cnt, out);
}